// Round 1
// baseline (2040.137 us; speedup 1.0000x reference)
//
#include <hip/hip_runtime.h>
#include <hip/hip_bf16.h>
#include <math.h>

// Problem constants (from reference): B=4, T=2048, D=2048, E=4, H=8192, TOPK=2, CAP=N/E
#define N_TOK 8192
#define DMODEL 2048
#define NEXP 4
#define HDIM 8192
#define CAP 2048

typedef __attribute__((ext_vector_type(4))) float f32x4;
typedef __attribute__((ext_vector_type(8))) short s16x8;
typedef __attribute__((ext_vector_type(4))) unsigned short u16x4;
typedef __attribute__((ext_vector_type(4))) unsigned int u32x4;

__device__ __forceinline__ unsigned short f2bf(float f) {
  __hip_bfloat16 h = __float2bfloat16(f);  // RNE
  return __builtin_bit_cast(unsigned short, h);
}

// ---------------- Router: logits = x @ Wg + bg (f64 accum), top-2, softmax probs ----------------
// One wave per token. Writes dense probs[token][4] (0 for unassigned experts).
__global__ __launch_bounds__(256) void router_kernel(
    const float* __restrict__ x, const float* __restrict__ Wg,
    const float* __restrict__ bg, float* __restrict__ probs) {
  int token = blockIdx.x * 4 + (threadIdx.x >> 6);
  int lane = threadIdx.x & 63;
  const float* xr = x + (size_t)token * DMODEL;
  double a0 = 0, a1 = 0, a2 = 0, a3 = 0;
  for (int i = lane; i < DMODEL; i += 64) {
    float xv = xr[i];
    float4 w = ((const float4*)Wg)[i];  // Wg[i][0..3] contiguous
    a0 += (double)xv * (double)w.x;
    a1 += (double)xv * (double)w.y;
    a2 += (double)xv * (double)w.z;
    a3 += (double)xv * (double)w.w;
  }
  for (int off = 32; off > 0; off >>= 1) {
    a0 += __shfl_down(a0, off);
    a1 += __shfl_down(a1, off);
    a2 += __shfl_down(a2, off);
    a3 += __shfl_down(a3, off);
  }
  if (lane == 0) {
    float l[4] = {(float)(a0 + (double)bg[0]), (float)(a1 + (double)bg[1]),
                  (float)(a2 + (double)bg[2]), (float)(a3 + (double)bg[3])};
    // top-2 with jax.lax.top_k tie semantics (lower index wins ties)
    int e1 = 0;
    for (int e = 1; e < 4; ++e) if (l[e] > l[e1]) e1 = e;
    int e2 = (e1 == 0) ? 1 : 0;
    for (int e = e2 + 1; e < 4; ++e) { if (e == e1) continue; if (l[e] > l[e2]) e2 = e; }
    float d = l[e2] - l[e1];        // <= 0
    float ex = expf(d);
    float z = 1.0f + ex;            // softmax denom (only two finite entries)
    float pr[4] = {0.f, 0.f, 0.f, 0.f};
    pr[e1] = 1.0f / z;
    pr[e2] = ex / z;
    float* pp = probs + (size_t)token * 4;
    pp[0] = pr[0]; pp[1] = pr[1]; pp[2] = pr[2]; pp[3] = pr[3];
  }
}

// ---------------- Capacity selection: per expert, exact top-2048 by (prob desc, idx asc) -------
// One block per expert; bitonic sort of 8192 64-bit keys in LDS. Exactly matches lax.top_k order.
__global__ __launch_bounds__(256) void select_kernel(
    const float* __restrict__ probs, int* __restrict__ sel_idx, float* __restrict__ sel_p) {
  __shared__ unsigned long long keys[N_TOK];  // 64 KiB
  int e = blockIdx.x;
  for (int i = threadIdx.x; i < N_TOK; i += blockDim.x) {
    float p = probs[(size_t)i * 4 + e];
    unsigned hi = (p > 0.f) ? __float_as_uint(p) : 0u;  // p>0 iff assigned; bits monotone for p>=0
    keys[i] = ((unsigned long long)hi << 32) | (unsigned)(0xFFFFFFFFu - (unsigned)i);
  }
  __syncthreads();
  for (int k = 2; k <= N_TOK; k <<= 1) {
    for (int j = k >> 1; j > 0; j >>= 1) {
      for (int i = threadIdx.x; i < N_TOK; i += blockDim.x) {
        int ixj = i ^ j;
        if (ixj > i) {
          bool ddd = ((i & k) == 0);
          unsigned long long a = keys[i], b = keys[ixj];
          if ((a < b) == ddd) { keys[i] = b; keys[ixj] = a; }  // descending overall
        }
      }
      __syncthreads();
    }
  }
  for (int c = threadIdx.x; c < CAP; c += blockDim.x) {
    unsigned long long kk = keys[c];
    unsigned idx = 0xFFFFFFFFu - (unsigned)(kk & 0xFFFFFFFFu);
    sel_idx[e * CAP + c] = (int)idx;
    sel_p[e * CAP + c] = __uint_as_float((unsigned)(kk >> 32));  // 0.0 for unfilled slots
  }
}

// ---------------- Gather selected token rows, convert f32 -> bf16 ----------------
__global__ __launch_bounds__(256) void gather_kernel(
    const float* __restrict__ x, const int* __restrict__ sel_idx,
    unsigned short* __restrict__ tok) {
  int row = blockIdx.x;  // e*CAP + c
  int t = sel_idx[row];
  const float4* src = (const float4*)(x + (size_t)t * DMODEL);
  u16x4* dst = (u16x4*)(tok + (size_t)row * DMODEL);
  for (int i = threadIdx.x; i < DMODEL / 4; i += blockDim.x) {
    float4 v = src[i];
    u16x4 w = {f2bf(v.x), f2bf(v.y), f2bf(v.z), f2bf(v.w)};
    dst[i] = w;
  }
}

__device__ __forceinline__ float gelu_exact(float v) {
  return 0.5f * v * (1.0f + erff(v * 0.70710678118654752f));
}

// ---------------- Tiled bf16 MFMA GEMM ----------------
// C[M,N] = A[M,K](bf16) * B[K,N](f32, converted to bf16 in staging).
// 128x128 tile, BK=64, 4 waves (2x2), each wave 64x64 = 4x4 frags of 16x16x32.
// EPI 0: C -> exact gelu -> bf16 store (h buffer).  EPI 1: C * p[m] scatter-added into out rows.
template <int EPI>
__global__ __launch_bounds__(256) void gemm_kernel(
    const unsigned short* __restrict__ A, const float* __restrict__ B, void* __restrict__ C,
    const int* __restrict__ sel_idx, const float* __restrict__ sel_p,
    int M, int N, int K) {
  __shared__ unsigned short As[128 * 72];  // [m][k], padded row (72*2=144B) -> 2-way bank alias only
  __shared__ unsigned short Bs[128 * 72];  // B^T: [n][k]
  const int tid = threadIdx.x;
  const int lane = tid & 63;
  const int wid = tid >> 6;
  const int wm = wid >> 1, wn = wid & 1;
  const int m0 = blockIdx.y * 128, n0 = blockIdx.x * 128;

  f32x4 acc[4][4];
  for (int i = 0; i < 4; ++i)
    for (int j = 0; j < 4; ++j) acc[i][j] = (f32x4){0.f, 0.f, 0.f, 0.f};

  const int ca = tid & 7, ra = tid >> 3;   // A staging: 16B chunk, row
  const int jb = tid & 31, gb = tid >> 5;  // B staging: n-chunk (4 cols), k-group (4 rows)

  for (int kt = 0; kt < K; kt += 64) {
    // stage A tile [128][64] bf16 via 16B copies
    for (int p = 0; p < 4; ++p) {
      int r = ra + 32 * p;
      u32x4 v = *(const u32x4*)(A + (size_t)(m0 + r) * K + kt + ca * 8);
      *(u32x4*)&As[r * 72 + ca * 8] = v;
    }
    // stage B tile transposed+converted: Bs[n][k] = bf16(B[kt+k][n0+n])
    for (int h = 0; h < 2; ++h) {
      int kk = gb * 4 + h * 32;
      const float* bp = B + (size_t)(kt + kk) * N + n0 + jb * 4;
      float4 q0 = *(const float4*)bp;
      float4 q1 = *(const float4*)(bp + (size_t)N);
      float4 q2 = *(const float4*)(bp + 2 * (size_t)N);
      float4 q3 = *(const float4*)(bp + 3 * (size_t)N);
      u16x4 w0 = {f2bf(q0.x), f2bf(q1.x), f2bf(q2.x), f2bf(q3.x)};
      u16x4 w1 = {f2bf(q0.y), f2bf(q1.y), f2bf(q2.y), f2bf(q3.y)};
      u16x4 w2 = {f2bf(q0.z), f2bf(q1.z), f2bf(q2.z), f2bf(q3.z)};
      u16x4 w3 = {f2bf(q0.w), f2bf(q1.w), f2bf(q2.w), f2bf(q3.w)};
      *(u16x4*)&Bs[(jb * 4 + 0) * 72 + kk] = w0;
      *(u16x4*)&Bs[(jb * 4 + 1) * 72 + kk] = w1;
      *(u16x4*)&Bs[(jb * 4 + 2) * 72 + kk] = w2;
      *(u16x4*)&Bs[(jb * 4 + 3) * 72 + kk] = w3;
    }
    __syncthreads();
    for (int kb = 0; kb < 2; ++kb) {
      const int kcol = kb * 32 + (lane >> 4) * 8;
      s16x8 av[4], bv[4];
      for (int mf = 0; mf < 4; ++mf)
        av[mf] = *(const s16x8*)&As[(wm * 64 + mf * 16 + (lane & 15)) * 72 + kcol];
      for (int nf = 0; nf < 4; ++nf)
        bv[nf] = *(const s16x8*)&Bs[(wn * 64 + nf * 16 + (lane & 15)) * 72 + kcol];
      for (int mf = 0; mf < 4; ++mf)
        for (int nf = 0; nf < 4; ++nf)
          acc[mf][nf] = __builtin_amdgcn_mfma_f32_16x16x32_bf16(av[mf], bv[nf], acc[mf][nf], 0, 0, 0);
    }
    __syncthreads();
  }

  // epilogue (C layout: col = lane&15, row = (lane>>4)*4 + reg)
  if (EPI == 0) {
    unsigned short* H = (unsigned short*)C;
    for (int mf = 0; mf < 4; ++mf) {
      int rowb = m0 + wm * 64 + mf * 16 + ((lane >> 4) << 2);
      for (int nf = 0; nf < 4; ++nf) {
        int col = n0 + wn * 64 + nf * 16 + (lane & 15);
        for (int r = 0; r < 4; ++r) {
          H[(size_t)(rowb + r) * N + col] = f2bf(gelu_exact(acc[mf][nf][r]));
        }
      }
    }
  } else {
    float* O = (float*)C;
    for (int mf = 0; mf < 4; ++mf) {
      int rowb = m0 + wm * 64 + mf * 16 + ((lane >> 4) << 2);
      int tk[4];
      float pv[4];
      for (int r = 0; r < 4; ++r) { tk[r] = sel_idx[rowb + r]; pv[r] = sel_p[rowb + r]; }
      for (int nf = 0; nf < 4; ++nf) {
        int col = n0 + wn * 64 + nf * 16 + (lane & 15);
        for (int r = 0; r < 4; ++r) {
          float* po = &O[(size_t)tk[r] * DMODEL + col];
          *po += acc[mf][nf][r] * pv[r];  // race-free: distinct tokens within an expert,
        }                                 // experts serialized by stream order
      }
    }
  }
}

extern "C" void kernel_launch(void* const* d_in, const int* in_sizes, int n_in,
                              void* d_out, int out_size, void* d_ws, size_t ws_size,
                              hipStream_t stream) {
  const float* x  = (const float*)d_in[0];
  const float* Wg = (const float*)d_in[1];
  const float* bg = (const float*)d_in[2];
  const float* W1 = (const float*)d_in[3];
  const float* W2 = (const float*)d_in[4];
  float* out = (float*)d_out;

  char* ws = (char*)d_ws;
  float* probs   = (float*)ws;                                   // 8192*4*4   = 128 KiB
  int*   sel_idx = (int*)(ws + 131072);                          // 4*2048*4   = 32 KiB
  float* sel_p   = (float*)(ws + 131072 + 32768);                // 32 KiB
  unsigned short* tok = (unsigned short*)(ws + 196608);          // 4*2048*2048*2 = 32 MiB
  unsigned short* h   = (unsigned short*)(ws + 196608 + 33554432);  // 2048*8192*2 = 32 MiB

  hipMemsetAsync(d_out, 0, (size_t)out_size * sizeof(float), stream);

  router_kernel<<<N_TOK / 4, 256, 0, stream>>>(x, Wg, bg, probs);
  select_kernel<<<NEXP, 256, 0, stream>>>(probs, sel_idx, sel_p);
  gather_kernel<<<NEXP * CAP, 256, 0, stream>>>(x, sel_idx, tok);

  for (int e = 0; e < NEXP; ++e) {
    gemm_kernel<0><<<dim3(HDIM / 128, CAP / 128), 256, 0, stream>>>(
        tok + (size_t)e * CAP * DMODEL, W1 + (size_t)e * DMODEL * HDIM, h,
        nullptr, nullptr, CAP, HDIM, DMODEL);
    gemm_kernel<1><<<dim3(DMODEL / 128, CAP / 128), 256, 0, stream>>>(
        h, W2 + (size_t)e * HDIM * DMODEL, out,
        sel_idx + e * CAP, sel_p + e * CAP, CAP, DMODEL, HDIM);
  }
}

// Round 2
// 1418.540 us; speedup vs baseline: 1.4382x; 1.4382x over previous
//
#include <hip/hip_runtime.h>
#include <hip/hip_bf16.h>
#include <math.h>
#include <stdint.h>

// Problem constants: B=4, T=2048, D=2048, E=4, H=8192, TOPK=2, CAP=N/E
#define N_TOK 8192
#define DMODEL 2048
#define NEXP 4
#define HDIM 8192
#define CAP 2048

typedef __attribute__((ext_vector_type(4))) float f32x4;
typedef __attribute__((ext_vector_type(8))) short s16x8;
typedef __attribute__((ext_vector_type(4))) unsigned short u16x4;

__device__ __forceinline__ unsigned short f2bf(float f) {
  __hip_bfloat16 h = __float2bfloat16(f);  // RNE
  return __builtin_bit_cast(unsigned short, h);
}

// global->LDS direct copy, 16 B per lane. LDS dest must be wave-uniform base;
// HW writes lane i at base + i*16. AS casts via integer (CK pattern): generic
// LDS pointer's low 32 bits are the LDS offset; global generic == AS1 numerically.
__device__ __forceinline__ void gload_lds16(const void* g, void* l) {
  __builtin_amdgcn_global_load_lds(
      (const __attribute__((address_space(1))) unsigned int*)(uintptr_t)g,
      (__attribute__((address_space(3))) unsigned int*)(unsigned int)(uintptr_t)l,
      16, 0, 0);
}

// ---------------- Router: logits = x @ Wg + bg (f64 accum), top-2, softmax probs ----------------
__global__ __launch_bounds__(256) void router_kernel(
    const float* __restrict__ x, const float* __restrict__ Wg,
    const float* __restrict__ bg, float* __restrict__ probs) {
  int token = blockIdx.x * 4 + (threadIdx.x >> 6);
  int lane = threadIdx.x & 63;
  const float* xr = x + (size_t)token * DMODEL;
  double a0 = 0, a1 = 0, a2 = 0, a3 = 0;
  for (int i = lane; i < DMODEL; i += 64) {
    float xv = xr[i];
    float4 w = ((const float4*)Wg)[i];
    a0 += (double)xv * (double)w.x;
    a1 += (double)xv * (double)w.y;
    a2 += (double)xv * (double)w.z;
    a3 += (double)xv * (double)w.w;
  }
  for (int off = 32; off > 0; off >>= 1) {
    a0 += __shfl_down(a0, off);
    a1 += __shfl_down(a1, off);
    a2 += __shfl_down(a2, off);
    a3 += __shfl_down(a3, off);
  }
  if (lane == 0) {
    float l[4] = {(float)(a0 + (double)bg[0]), (float)(a1 + (double)bg[1]),
                  (float)(a2 + (double)bg[2]), (float)(a3 + (double)bg[3])};
    int e1 = 0;
    for (int e = 1; e < 4; ++e) if (l[e] > l[e1]) e1 = e;
    int e2 = (e1 == 0) ? 1 : 0;
    for (int e = e2 + 1; e < 4; ++e) { if (e == e1) continue; if (l[e] > l[e2]) e2 = e; }
    float d = l[e2] - l[e1];
    float ex = expf(d);
    float z = 1.0f + ex;
    float pr[4] = {0.f, 0.f, 0.f, 0.f};
    pr[e1] = 1.0f / z;
    pr[e2] = ex / z;
    float* pp = probs + (size_t)token * 4;
    pp[0] = pr[0]; pp[1] = pr[1]; pp[2] = pr[2]; pp[3] = pr[3];
  }
}

// ---------------- Capacity selection: exact top-2048 per expert by (prob desc, idx asc) --------
__global__ __launch_bounds__(256) void select_kernel(
    const float* __restrict__ probs, int* __restrict__ sel_idx, float* __restrict__ sel_p) {
  __shared__ unsigned long long keys[N_TOK];  // 64 KiB
  int e = blockIdx.x;
  for (int i = threadIdx.x; i < N_TOK; i += blockDim.x) {
    float p = probs[(size_t)i * 4 + e];
    unsigned hi = (p > 0.f) ? __float_as_uint(p) : 0u;
    keys[i] = ((unsigned long long)hi << 32) | (unsigned)(0xFFFFFFFFu - (unsigned)i);
  }
  __syncthreads();
  for (int k = 2; k <= N_TOK; k <<= 1) {
    for (int j = k >> 1; j > 0; j >>= 1) {
      for (int i = threadIdx.x; i < N_TOK; i += blockDim.x) {
        int ixj = i ^ j;
        if (ixj > i) {
          bool ddd = ((i & k) == 0);
          unsigned long long a = keys[i], b = keys[ixj];
          if ((a < b) == ddd) { keys[i] = b; keys[ixj] = a; }
        }
      }
      __syncthreads();
    }
  }
  for (int c = threadIdx.x; c < CAP; c += blockDim.x) {
    unsigned long long kk = keys[c];
    unsigned idx = 0xFFFFFFFFu - (unsigned)(kk & 0xFFFFFFFFu);
    sel_idx[e * CAP + c] = (int)idx;
    sel_p[e * CAP + c] = __uint_as_float((unsigned)(kk >> 32));
  }
}

// ---------------- Gather selected token rows, f32 -> bf16 ----------------
__global__ __launch_bounds__(256) void gather_kernel(
    const float* __restrict__ x, const int* __restrict__ sel_idx,
    unsigned short* __restrict__ tok) {
  int row = blockIdx.x;
  int t = sel_idx[row];
  const float4* src = (const float4*)(x + (size_t)t * DMODEL);
  u16x4* dst = (u16x4*)(tok + (size_t)row * DMODEL);
  for (int i = threadIdx.x; i < DMODEL / 4; i += blockDim.x) {
    float4 v = src[i];
    u16x4 w = {f2bf(v.x), f2bf(v.y), f2bf(v.z), f2bf(v.w)};
    dst[i] = w;
  }
}

// ---------------- Transpose + convert: W[K][N] f32 -> WT[N][K] bf16, 64x64 tiles ----------------
__global__ __launch_bounds__(256) void transpose_convert_kernel(
    const float* __restrict__ W, unsigned short* __restrict__ WT, int K, int N) {
  __shared__ unsigned short tile[64][68];  // pad 4 -> row 136 B (8B aligned, breaks pow2 banks)
  const size_t eoff = (size_t)blockIdx.z * (size_t)K * N;
  const float* Wp = W + eoff;
  unsigned short* Tp = WT + eoff;
  const int n0 = blockIdx.x * 64, k0 = blockIdx.y * 64;
  const int tid = threadIdx.x;
  const int nn4 = tid & 15, kk = tid >> 4;
#pragma unroll
  for (int p = 0; p < 4; ++p) {
    int k = kk + p * 16;
    float4 v = *(const float4*)&Wp[(size_t)(k0 + k) * N + n0 + nn4 * 4];
    tile[nn4 * 4 + 0][k] = f2bf(v.x);
    tile[nn4 * 4 + 1][k] = f2bf(v.y);
    tile[nn4 * 4 + 2][k] = f2bf(v.z);
    tile[nn4 * 4 + 3][k] = f2bf(v.w);
  }
  __syncthreads();
  const int nw = tid >> 4, cw = (tid & 15) * 4;
#pragma unroll
  for (int p = 0; p < 4; ++p) {
    int n = nw + p * 16;
    u16x4 v = *(const u16x4*)&tile[n][cw];
    *(u16x4*)&Tp[(size_t)(n0 + n) * K + k0 + cw] = v;
  }
}

// ---------------- m97-structure bf16 GEMM ----------------
// C[M,N] = A[M,K] * Bt[N,K]^T, both bf16 k-contiguous. 128x128 tile, BK=64,
// 4 waves (2x2), global_load_lds width-16 staging into linear LDS, 2-barrier K-loop.
// Expert weight panel selected by (m0>>11)*b_stride (0 => single panel).
// EPI 0: exact GELU -> bf16 store. EPI 1: atomicAdd(C[sel_idx[m]] , acc*sel_p[m]).
template <int EPI>
__global__ __launch_bounds__(256) void gemm_kernel(
    const unsigned short* __restrict__ A, const unsigned short* __restrict__ Bt,
    void* __restrict__ C, const int* __restrict__ sel_idx, const float* __restrict__ sel_p,
    int M, int N, int K, size_t b_stride) {
  __shared__ unsigned short As[128 * 64];  // [m][k] linear (global_load_lds requires it)
  __shared__ unsigned short Bs[128 * 64];  // [n][k] linear
  const int tid = threadIdx.x;
  const int lane = tid & 63;
  const int w = tid >> 6;
  const int wm = w >> 1, wn = w & 1;
  const int m0 = blockIdx.y * 128, n0 = blockIdx.x * 128;
  const unsigned short* Bp = Bt + (size_t)(m0 >> 11) * b_stride;

  f32x4 acc[4][4];
#pragma unroll
  for (int i = 0; i < 4; ++i)
#pragma unroll
    for (int j = 0; j < 4; ++j) acc[i][j] = (f32x4){0.f, 0.f, 0.f, 0.f};

  const int lrow = lane >> 3;   // 0..7 rows per wave-issue
  const int lchunk = lane & 7;  // 16B chunk within row
  const unsigned short* ga = A + (size_t)(m0 + w * 8 + lrow) * K + lchunk * 8;
  const unsigned short* gb = Bp + (size_t)(n0 + w * 8 + lrow) * K + lchunk * 8;

  for (int kt = 0; kt < K; kt += 64) {
#pragma unroll
    for (int i = 0; i < 4; ++i) {
      gload_lds16(ga + (size_t)(i * 32) * K + kt, &As[(i * 32 + w * 8) * 64]);
      gload_lds16(gb + (size_t)(i * 32) * K + kt, &Bs[(i * 32 + w * 8) * 64]);
    }
    __syncthreads();  // compiler drains vmcnt(0) before barrier -> LDS ready
#pragma unroll
    for (int kb = 0; kb < 2; ++kb) {
      const int kcol = kb * 32 + (lane >> 4) * 8;
      s16x8 av[4], bv[4];
#pragma unroll
      for (int mf = 0; mf < 4; ++mf)
        av[mf] = *(const s16x8*)&As[(wm * 64 + mf * 16 + (lane & 15)) * 64 + kcol];
#pragma unroll
      for (int nf = 0; nf < 4; ++nf)
        bv[nf] = *(const s16x8*)&Bs[(wn * 64 + nf * 16 + (lane & 15)) * 64 + kcol];
#pragma unroll
      for (int mf = 0; mf < 4; ++mf)
#pragma unroll
        for (int nf = 0; nf < 4; ++nf)
          acc[mf][nf] = __builtin_amdgcn_mfma_f32_16x16x32_bf16(av[mf], bv[nf], acc[mf][nf], 0, 0, 0);
    }
    __syncthreads();
  }

  // C layout per 16x16 frag: col = lane&15, row = (lane>>4)*4 + reg
  if (EPI == 0) {
    unsigned short* Hc = (unsigned short*)C;
#pragma unroll
    for (int mf = 0; mf < 4; ++mf) {
      int rowb = m0 + wm * 64 + mf * 16 + ((lane >> 4) << 2);
#pragma unroll
      for (int nf = 0; nf < 4; ++nf) {
        int col = n0 + wn * 64 + nf * 16 + (lane & 15);
#pragma unroll
        for (int r = 0; r < 4; ++r) {
          float v = acc[mf][nf][r];
          float g = 0.5f * v * (1.0f + erff(v * 0.70710678118654752f));
          Hc[(size_t)(rowb + r) * N + col] = f2bf(g);
        }
      }
    }
  } else {
    float* O = (float*)C;
#pragma unroll
    for (int mf = 0; mf < 4; ++mf) {
      int rowb = m0 + wm * 64 + mf * 16 + ((lane >> 4) << 2);
      int tk[4];
      float pv[4];
#pragma unroll
      for (int r = 0; r < 4; ++r) { tk[r] = sel_idx[rowb + r]; pv[r] = sel_p[rowb + r]; }
#pragma unroll
      for (int nf = 0; nf < 4; ++nf) {
        int col = n0 + wn * 64 + nf * 16 + (lane & 15);
#pragma unroll
        for (int r = 0; r < 4; ++r)
          atomicAdd(&O[(size_t)tk[r] * DMODEL + col], acc[mf][nf][r] * pv[r]);
      }
    }
  }
}

extern "C" void kernel_launch(void* const* d_in, const int* in_sizes, int n_in,
                              void* d_out, int out_size, void* d_ws, size_t ws_size,
                              hipStream_t stream) {
  const float* x  = (const float*)d_in[0];
  const float* Wg = (const float*)d_in[1];
  const float* bg = (const float*)d_in[2];
  const float* W1 = (const float*)d_in[3];
  const float* W2 = (const float*)d_in[4];
  float* out = (float*)d_out;

  char* ws = (char*)d_ws;
  float* probs   = (float*)ws;                      // 128 KiB
  int*   sel_idx = (int*)(ws + 131072);             // 32 KiB
  float* sel_p   = (float*)(ws + 131072 + 32768);   // 32 KiB
  unsigned short* tok = (unsigned short*)(ws + 196608);  // 8192x2048 bf16 = 32 MiB
  const size_t tok_b = (size_t)N_TOK * DMODEL * 2;
  const size_t h_b   = (size_t)N_TOK * HDIM * 2;          // 128 MiB (merged)
  const size_t w_b   = (size_t)NEXP * DMODEL * HDIM * 2;  // 128 MiB each
  const size_t base  = 196608 + tok_b;

  hipMemsetAsync(d_out, 0, (size_t)out_size * sizeof(float), stream);
  router_kernel<<<N_TOK / 4, 256, 0, stream>>>(x, Wg, bg, probs);
  select_kernel<<<NEXP, 256, 0, stream>>>(probs, sel_idx, sel_p);
  gather_kernel<<<NEXP * CAP, 256, 0, stream>>>(x, sel_idx, tok);

  if (ws_size >= base + h_b + 2 * w_b) {
    // Merged path: one dispatch per stage across all 4 experts.
    unsigned short* h   = (unsigned short*)(ws + base);
    unsigned short* W1T = (unsigned short*)(ws + base + h_b);
    unsigned short* W2T = (unsigned short*)(ws + base + h_b + w_b);
    transpose_convert_kernel<<<dim3(HDIM / 64, DMODEL / 64, NEXP), 256, 0, stream>>>(
        W1, W1T, DMODEL, HDIM);
    transpose_convert_kernel<<<dim3(DMODEL / 64, HDIM / 64, NEXP), 256, 0, stream>>>(
        W2, W2T, HDIM, DMODEL);
    gemm_kernel<0><<<dim3(HDIM / 128, N_TOK / 128), 256, 0, stream>>>(
        tok, W1T, h, nullptr, nullptr, N_TOK, HDIM, DMODEL, (size_t)DMODEL * HDIM);
    gemm_kernel<1><<<dim3(DMODEL / 128, N_TOK / 128), 256, 0, stream>>>(
        h, W2T, out, sel_idx, sel_p, N_TOK, DMODEL, HDIM, (size_t)DMODEL * HDIM);
  } else {
    // Fallback: per-expert, reuse one 32 MiB weight buffer + 32 MiB h buffer.
    unsigned short* h    = (unsigned short*)(ws + base);                 // CAPxHDIM = 32 MiB
    unsigned short* wbuf = (unsigned short*)(ws + base + (size_t)CAP * HDIM * 2);
    for (int e = 0; e < NEXP; ++e) {
      transpose_convert_kernel<<<dim3(HDIM / 64, DMODEL / 64, 1), 256, 0, stream>>>(
          W1 + (size_t)e * DMODEL * HDIM, wbuf, DMODEL, HDIM);
      gemm_kernel<0><<<dim3(HDIM / 128, CAP / 128), 256, 0, stream>>>(
          tok + (size_t)e * CAP * DMODEL, wbuf, h, nullptr, nullptr, CAP, HDIM, DMODEL, 0);
      transpose_convert_kernel<<<dim3(DMODEL / 64, HDIM / 64, 1), 256, 0, stream>>>(
          W2 + (size_t)e * HDIM * DMODEL, wbuf, HDIM, DMODEL);
      gemm_kernel<1><<<dim3(DMODEL / 128, CAP / 128), 256, 0, stream>>>(
          h, wbuf, out, sel_idx + e * CAP, sel_p + e * CAP, CAP, DMODEL, HDIM, 0);
    }
  }
}

// Round 3
// 1060.104 us; speedup vs baseline: 1.9245x; 1.3381x over previous
//
#include <hip/hip_runtime.h>
#include <hip/hip_bf16.h>
#include <math.h>
#include <stdint.h>

// Problem constants: B=4, T=2048, D=2048, E=4, H=8192, TOPK=2, CAP=N/E
#define N_TOK 8192
#define DMODEL 2048
#define NEXP 4
#define HDIM 8192
#define CAP 2048

typedef __attribute__((ext_vector_type(4))) float f32x4;
typedef __attribute__((ext_vector_type(8))) short s16x8;
typedef __attribute__((ext_vector_type(4))) unsigned short u16x4;

__device__ __forceinline__ unsigned short f2bf(float f) {
  __hip_bfloat16 h = __float2bfloat16(f);  // RNE
  return __builtin_bit_cast(unsigned short, h);
}

// global->LDS direct copy, 16 B per lane. LDS dest is wave-uniform base;
// HW writes lane i at base + i*16. Global source address is per-lane.
__device__ __forceinline__ void gload_lds16(const void* g, void* l) {
  __builtin_amdgcn_global_load_lds(
      (const __attribute__((address_space(1))) unsigned int*)(uintptr_t)g,
      (__attribute__((address_space(3))) unsigned int*)(unsigned int)(uintptr_t)l,
      16, 0, 0);
}

// ---------------- Router: logits = x @ Wg + bg (f64 accum), top-2, softmax probs ----------------
__global__ __launch_bounds__(256) void router_kernel(
    const float* __restrict__ x, const float* __restrict__ Wg,
    const float* __restrict__ bg, float* __restrict__ probs) {
  int token = blockIdx.x * 4 + (threadIdx.x >> 6);
  int lane = threadIdx.x & 63;
  const float* xr = x + (size_t)token * DMODEL;
  double a0 = 0, a1 = 0, a2 = 0, a3 = 0;
  for (int i = lane; i < DMODEL; i += 64) {
    float xv = xr[i];
    float4 w = ((const float4*)Wg)[i];
    a0 += (double)xv * (double)w.x;
    a1 += (double)xv * (double)w.y;
    a2 += (double)xv * (double)w.z;
    a3 += (double)xv * (double)w.w;
  }
  for (int off = 32; off > 0; off >>= 1) {
    a0 += __shfl_down(a0, off);
    a1 += __shfl_down(a1, off);
    a2 += __shfl_down(a2, off);
    a3 += __shfl_down(a3, off);
  }
  if (lane == 0) {
    float l[4] = {(float)(a0 + (double)bg[0]), (float)(a1 + (double)bg[1]),
                  (float)(a2 + (double)bg[2]), (float)(a3 + (double)bg[3])};
    int e1 = 0;
    for (int e = 1; e < 4; ++e) if (l[e] > l[e1]) e1 = e;
    int e2 = (e1 == 0) ? 1 : 0;
    for (int e = e2 + 1; e < 4; ++e) { if (e == e1) continue; if (l[e] > l[e2]) e2 = e; }
    float d = l[e2] - l[e1];
    float ex = expf(d);
    float z = 1.0f + ex;
    float pr[4] = {0.f, 0.f, 0.f, 0.f};
    pr[e1] = 1.0f / z;
    pr[e2] = ex / z;
    float* pp = probs + (size_t)token * 4;
    pp[0] = pr[0]; pp[1] = pr[1]; pp[2] = pr[2]; pp[3] = pr[3];
  }
}

// ---------------- Capacity selection: exact top-2048 per expert by (prob desc, idx asc) --------
__global__ __launch_bounds__(256) void select_kernel(
    const float* __restrict__ probs, int* __restrict__ sel_idx, float* __restrict__ sel_p) {
  __shared__ unsigned long long keys[N_TOK];  // 64 KiB
  int e = blockIdx.x;
  for (int i = threadIdx.x; i < N_TOK; i += blockDim.x) {
    float p = probs[(size_t)i * 4 + e];
    unsigned hi = (p > 0.f) ? __float_as_uint(p) : 0u;
    keys[i] = ((unsigned long long)hi << 32) | (unsigned)(0xFFFFFFFFu - (unsigned)i);
  }
  __syncthreads();
  for (int k = 2; k <= N_TOK; k <<= 1) {
    for (int j = k >> 1; j > 0; j >>= 1) {
      for (int i = threadIdx.x; i < N_TOK; i += blockDim.x) {
        int ixj = i ^ j;
        if (ixj > i) {
          bool ddd = ((i & k) == 0);
          unsigned long long a = keys[i], b = keys[ixj];
          if ((a < b) == ddd) { keys[i] = b; keys[ixj] = a; }
        }
      }
      __syncthreads();
    }
  }
  for (int c = threadIdx.x; c < CAP; c += blockDim.x) {
    unsigned long long kk = keys[c];
    unsigned idx = 0xFFFFFFFFu - (unsigned)(kk & 0xFFFFFFFFu);
    sel_idx[e * CAP + c] = (int)idx;
    sel_p[e * CAP + c] = __uint_as_float((unsigned)(kk >> 32));
  }
}

// ---------------- Gather selected token rows, f32 -> bf16 ----------------
__global__ __launch_bounds__(256) void gather_kernel(
    const float* __restrict__ x, const int* __restrict__ sel_idx,
    unsigned short* __restrict__ tok) {
  int row = blockIdx.x;
  int t = sel_idx[row];
  const float4* src = (const float4*)(x + (size_t)t * DMODEL);
  u16x4* dst = (u16x4*)(tok + (size_t)row * DMODEL);
  for (int i = threadIdx.x; i < DMODEL / 4; i += blockDim.x) {
    float4 v = src[i];
    u16x4 w = {f2bf(v.x), f2bf(v.y), f2bf(v.z), f2bf(v.w)};
    dst[i] = w;
  }
}

// ---------------- Transpose + convert: W[K][N] f32 -> WT[N][K] bf16, 64x64 tiles ----------------
__global__ __launch_bounds__(256) void transpose_convert_kernel(
    const float* __restrict__ W, unsigned short* __restrict__ WT, int K, int N) {
  __shared__ unsigned short tile[64][68];
  const size_t eoff = (size_t)blockIdx.z * (size_t)K * N;
  const float* Wp = W + eoff;
  unsigned short* Tp = WT + eoff;
  const int n0 = blockIdx.x * 64, k0 = blockIdx.y * 64;
  const int tid = threadIdx.x;
  const int nn4 = tid & 15, kk = tid >> 4;
#pragma unroll
  for (int p = 0; p < 4; ++p) {
    int k = kk + p * 16;
    float4 v = *(const float4*)&Wp[(size_t)(k0 + k) * N + n0 + nn4 * 4];
    tile[nn4 * 4 + 0][k] = f2bf(v.x);
    tile[nn4 * 4 + 1][k] = f2bf(v.y);
    tile[nn4 * 4 + 2][k] = f2bf(v.z);
    tile[nn4 * 4 + 3][k] = f2bf(v.w);
  }
  __syncthreads();
  const int nw = tid >> 4, cw = (tid & 15) * 4;
#pragma unroll
  for (int p = 0; p < 4; ++p) {
    int n = nw + p * 16;
    u16x4 v = *(const u16x4*)&tile[n][cw];
    *(u16x4*)&Tp[(size_t)(n0 + n) * K + k0 + cw] = v;
  }
}

// ---------------- 256x256 double-buffered pipelined bf16 GEMM ----------------
// C[M,N] = A[M,K] * Bt[N,K]^T (both bf16, k-contiguous rows). 512 thr = 8 waves (2Mx4N),
// per-wave 128x64 output = acc[8][4]. BK=64. LDS 128 KiB: 2 x (A 256x64 + B 256x64).
// T2 swizzle both sides (rule 21): global source chunk ^= row&7, ds_read chunk ^= row&7.
// Pipeline: prefetch tile t+1 (A at phase kb=0 start, B at phase kb=1 start) into buf^1
// while computing tile t from buf; single __syncthreads() (full vmcnt drain) per K-tile.
// EPI 0: exact GELU -> bf16. EPI 1: atomicAdd(out[sel_idx[m]], acc*sel_p[m]).
template <int EPI>
__global__ __launch_bounds__(512) void gemm_kernel(
    const unsigned short* __restrict__ A, const unsigned short* __restrict__ Bt,
    void* __restrict__ C, const int* __restrict__ sel_idx, const float* __restrict__ sel_p,
    int M, int N, int K, size_t b_stride) {
  __shared__ unsigned short sh[65536];  // [buf][A/B][row 0..255][k 0..63] = 128 KiB
  const int tid = threadIdx.x;
  const int lane = tid & 63;
  const int w = tid >> 6;          // wave 0..7
  const int wm = w >> 2, wn = w & 3;

  // XCD-aware bijective swizzle (grid sizes here are multiples of 8)
  const int nwg = gridDim.x * gridDim.y;
  const int cpx = nwg >> 3;
  int linear = blockIdx.y * gridDim.x + blockIdx.x;
  linear = (linear & 7) * cpx + (linear >> 3);
  const int bx = linear & (gridDim.x - 1);
  const int by = linear >> __builtin_ctz(gridDim.x);
  const int m0 = by * 256, n0 = bx * 256;
  const unsigned short* Bp = Bt + (size_t)(m0 >> 11) * b_stride;

  f32x4 acc[8][4];
#pragma unroll
  for (int i = 0; i < 8; ++i)
#pragma unroll
    for (int j = 0; j < 4; ++j) acc[i][j] = (f32x4){0.f, 0.f, 0.f, 0.f};

  // staging addressing: wave w stages rows [w*32, w*32+32) of A and of B.
  // lane -> row_off = lane>>3, chunk_g = (lane&7) ^ (lane>>3)  (inverse swizzle on source)
  const int srow = w * 32 + (lane >> 3);
  const int schunk = ((lane & 7) ^ (lane >> 3)) * 8;
  const unsigned short* gA = A + (size_t)(m0 + srow) * K + schunk;
  const unsigned short* gB = Bp + (size_t)(n0 + srow) * K + schunk;
  const int ldsA = w * 2048;            // ushort index of wave's A slice base
  const int ldsB = 16384 + w * 2048;    // B slice base

  // read addressing: swizzled k-chunk (ushort units), csw1 = csw0 ^ 32
  const int csw0 = (((lane >> 4) ^ (lane & 7)) << 3);
  const int arow = wm * 128 + (lane & 15);  // A frag base row (+ mf*16)
  const int brow = wn * 64 + (lane & 15);   // B frag base row (+ nf*16)

  // prologue: stage tile 0 into buf 0
#pragma unroll
  for (int i = 0; i < 4; ++i) {
    gload_lds16(gA + (size_t)(i * 8) * K, &sh[ldsA + i * 512]);
    gload_lds16(gB + (size_t)(i * 8) * K, &sh[ldsB + i * 512]);
  }
  __syncthreads();

  int buf = 0;
  for (int kt = 0; kt < K; kt += 64, buf ^= 1) {
    const int nb = buf ^ 1;
    const unsigned short* shA = &sh[buf * 32768];
    const unsigned short* shB = &sh[buf * 32768 + 16384];
    const bool pf = (kt + 64) < K;
    // ---- phase 0 (kb=0): issue A-prefetch, then compute ----
    if (pf) {
#pragma unroll
      for (int i = 0; i < 4; ++i)
        gload_lds16(gA + (size_t)(i * 8) * K + (kt + 64), &sh[nb * 32768 + ldsA + i * 512]);
    }
#pragma unroll
    for (int kb = 0; kb < 2; ++kb) {
      const int csw = csw0 ^ (kb << 5);
      s16x8 av[8], bv[4];
#pragma unroll
      for (int mf = 0; mf < 8; ++mf)
        av[mf] = *(const s16x8*)&shA[(arow + mf * 16) * 64 + csw];
#pragma unroll
      for (int nf = 0; nf < 4; ++nf)
        bv[nf] = *(const s16x8*)&shB[(brow + nf * 16) * 64 + csw];
      __builtin_amdgcn_s_setprio(1);
#pragma unroll
      for (int mf = 0; mf < 8; ++mf)
#pragma unroll
        for (int nf = 0; nf < 4; ++nf)
          acc[mf][nf] = __builtin_amdgcn_mfma_f32_16x16x32_bf16(av[mf], bv[nf], acc[mf][nf], 0, 0, 0);
      __builtin_amdgcn_s_setprio(0);
      // ---- between phases: issue B-prefetch ----
      if (kb == 0 && pf) {
#pragma unroll
        for (int i = 0; i < 4; ++i)
          gload_lds16(gB + (size_t)(i * 8) * K + (kt + 64), &sh[nb * 32768 + ldsB + i * 512]);
      }
    }
    __syncthreads();  // drains vmcnt(0): prefetched tile fully in LDS, all reads done
  }

  // epilogue (C frag layout: col = lane&15, row = (lane>>4)*4 + reg)
  if (EPI == 0) {
    unsigned short* Hc = (unsigned short*)C;
#pragma unroll
    for (int mf = 0; mf < 8; ++mf) {
      int rowb = m0 + wm * 128 + mf * 16 + ((lane >> 4) << 2);
#pragma unroll
      for (int nf = 0; nf < 4; ++nf) {
        int col = n0 + wn * 64 + nf * 16 + (lane & 15);
#pragma unroll
        for (int r = 0; r < 4; ++r) {
          float v = acc[mf][nf][r];
          float g = 0.5f * v * (1.0f + erff(v * 0.70710678118654752f));
          Hc[(size_t)(rowb + r) * N + col] = f2bf(g);
        }
      }
    }
  } else {
    float* O = (float*)C;
#pragma unroll
    for (int mf = 0; mf < 8; ++mf) {
      int rowb = m0 + wm * 128 + mf * 16 + ((lane >> 4) << 2);
      int tk[4];
      float pv[4];
#pragma unroll
      for (int r = 0; r < 4; ++r) { tk[r] = sel_idx[rowb + r]; pv[r] = sel_p[rowb + r]; }
#pragma unroll
      for (int nf = 0; nf < 4; ++nf) {
        int col = n0 + wn * 64 + nf * 16 + (lane & 15);
#pragma unroll
        for (int r = 0; r < 4; ++r)
          atomicAdd(&O[(size_t)tk[r] * DMODEL + col], acc[mf][nf][r] * pv[r]);
      }
    }
  }
}

extern "C" void kernel_launch(void* const* d_in, const int* in_sizes, int n_in,
                              void* d_out, int out_size, void* d_ws, size_t ws_size,
                              hipStream_t stream) {
  const float* x  = (const float*)d_in[0];
  const float* Wg = (const float*)d_in[1];
  const float* bg = (const float*)d_in[2];
  const float* W1 = (const float*)d_in[3];
  const float* W2 = (const float*)d_in[4];
  float* out = (float*)d_out;

  char* ws = (char*)d_ws;
  float* probs   = (float*)ws;                      // 128 KiB
  int*   sel_idx = (int*)(ws + 131072);             // 32 KiB
  float* sel_p   = (float*)(ws + 131072 + 32768);   // 32 KiB
  unsigned short* tok = (unsigned short*)(ws + 196608);  // 8192x2048 bf16 = 32 MiB
  const size_t tok_b = (size_t)N_TOK * DMODEL * 2;
  const size_t h_b   = (size_t)N_TOK * HDIM * 2;          // 128 MiB
  const size_t w_b   = (size_t)NEXP * DMODEL * HDIM * 2;  // 128 MiB each
  const size_t base  = 196608 + tok_b;

  hipMemsetAsync(d_out, 0, (size_t)out_size * sizeof(float), stream);
  router_kernel<<<N_TOK / 4, 256, 0, stream>>>(x, Wg, bg, probs);
  select_kernel<<<NEXP, 256, 0, stream>>>(probs, sel_idx, sel_p);
  gather_kernel<<<NEXP * CAP, 256, 0, stream>>>(x, sel_idx, tok);

  if (ws_size >= base + h_b + 2 * w_b) {
    // Merged path: one dispatch per GEMM stage across all 4 experts.
    unsigned short* h   = (unsigned short*)(ws + base);
    unsigned short* W1T = (unsigned short*)(ws + base + h_b);
    unsigned short* W2T = (unsigned short*)(ws + base + h_b + w_b);
    transpose_convert_kernel<<<dim3(HDIM / 64, DMODEL / 64, NEXP), 256, 0, stream>>>(
        W1, W1T, DMODEL, HDIM);
    transpose_convert_kernel<<<dim3(DMODEL / 64, HDIM / 64, NEXP), 256, 0, stream>>>(
        W2, W2T, HDIM, DMODEL);
    gemm_kernel<0><<<dim3(HDIM / 256, N_TOK / 256), 512, 0, stream>>>(
        tok, W1T, h, nullptr, nullptr, N_TOK, HDIM, DMODEL, (size_t)DMODEL * HDIM);
    gemm_kernel<1><<<dim3(DMODEL / 256, N_TOK / 256), 512, 0, stream>>>(
        h, W2T, out, sel_idx, sel_p, N_TOK, DMODEL, HDIM, (size_t)DMODEL * HDIM);
  } else {
    // Fallback: per-expert, one 128 MiB-free layout (reuse buffers).
    unsigned short* h    = (unsigned short*)(ws + base);                 // CAPxHDIM = 32 MiB
    unsigned short* wbuf = (unsigned short*)(ws + base + (size_t)CAP * HDIM * 2);
    for (int e = 0; e < NEXP; ++e) {
      transpose_convert_kernel<<<dim3(HDIM / 64, DMODEL / 64, 1), 256, 0, stream>>>(
          W1 + (size_t)e * DMODEL * HDIM, wbuf, DMODEL, HDIM);
      gemm_kernel<0><<<dim3(HDIM / 256, CAP / 256), 512, 0, stream>>>(
          tok + (size_t)e * CAP * DMODEL, wbuf, h, nullptr, nullptr, CAP, HDIM, DMODEL, 0);
      transpose_convert_kernel<<<dim3(DMODEL / 64, HDIM / 64, 1), 256, 0, stream>>>(
          W2 + (size_t)e * HDIM * DMODEL, wbuf, HDIM, DMODEL);
      gemm_kernel<1><<<dim3(DMODEL / 256, CAP / 256), 512, 0, stream>>>(
          h, wbuf, out, sel_idx + e * CAP, sel_p + e * CAP, CAP, DMODEL, HDIM, 0);
    }
  }
}

// Round 5
// 896.293 us; speedup vs baseline: 2.2762x; 1.1828x over previous
//
#include <hip/hip_runtime.h>
#include <hip/hip_bf16.h>
#include <math.h>
#include <stdint.h>

// Problem constants: B=4, T=2048, D=2048, E=4, H=8192, TOPK=2, CAP=N/E
#define N_TOK 8192
#define DMODEL 2048
#define NEXP 4
#define HDIM 8192
#define CAP 2048

typedef __attribute__((ext_vector_type(4))) float f32x4;
typedef __attribute__((ext_vector_type(8))) short s16x8;
typedef __attribute__((ext_vector_type(4))) unsigned short u16x4;

__device__ __forceinline__ unsigned short f2bf(float f) {
  __hip_bfloat16 h = __float2bfloat16(f);  // RNE
  return __builtin_bit_cast(unsigned short, h);
}

// global->LDS direct copy, 16 B per lane. LDS dest is wave-uniform base;
// HW writes lane i at base + i*16. Global source address is per-lane.
__device__ __forceinline__ void gload_lds16(const void* g, void* l) {
  __builtin_amdgcn_global_load_lds(
      (const __attribute__((address_space(1))) unsigned int*)(uintptr_t)g,
      (__attribute__((address_space(3))) unsigned int*)(unsigned int)(uintptr_t)l,
      16, 0, 0);
}

// ---------------- Router: logits = x @ Wg + bg (f64 accum), top-2 -> 64-bit sort keys --------
// key[e][i] = (float_bits(prob_e_i) << 32) | (0xFFFFFFFF - i); prob=0 for unassigned experts.
// Key order (desc) == lax.top_k order (prob desc, index asc). All keys distinct.
__global__ __launch_bounds__(256) void router_kernel(
    const float* __restrict__ x, const float* __restrict__ Wg,
    const float* __restrict__ bg, unsigned long long* __restrict__ keys) {
  int token = blockIdx.x * 4 + (threadIdx.x >> 6);
  int lane = threadIdx.x & 63;
  const float* xr = x + (size_t)token * DMODEL;
  double a0 = 0, a1 = 0, a2 = 0, a3 = 0;
  for (int i = lane; i < DMODEL; i += 64) {
    float xv = xr[i];
    float4 w = ((const float4*)Wg)[i];
    a0 += (double)xv * (double)w.x;
    a1 += (double)xv * (double)w.y;
    a2 += (double)xv * (double)w.z;
    a3 += (double)xv * (double)w.w;
  }
  for (int off = 32; off > 0; off >>= 1) {
    a0 += __shfl_down(a0, off);
    a1 += __shfl_down(a1, off);
    a2 += __shfl_down(a2, off);
    a3 += __shfl_down(a3, off);
  }
  if (lane == 0) {
    float l[4] = {(float)(a0 + (double)bg[0]), (float)(a1 + (double)bg[1]),
                  (float)(a2 + (double)bg[2]), (float)(a3 + (double)bg[3])};
    int e1 = 0;
    for (int e = 1; e < 4; ++e) if (l[e] > l[e1]) e1 = e;
    int e2 = (e1 == 0) ? 1 : 0;
    for (int e = e2 + 1; e < 4; ++e) { if (e == e1) continue; if (l[e] > l[e2]) e2 = e; }
    float d = l[e2] - l[e1];
    float ex = expf(d);
    float z = 1.0f + ex;
    float p1 = 1.0f / z, p2 = ex / z;
    unsigned lo = 0xFFFFFFFFu - (unsigned)token;
    for (int e = 0; e < 4; ++e) {
      unsigned hi = (e == e1) ? __float_as_uint(p1) : (e == e2) ? __float_as_uint(p2) : 0u;
      keys[(size_t)e * N_TOK + token] = ((unsigned long long)hi << 32) | lo;
    }
  }
}

// ---------------- Rank-based capacity selection: slot = #{j : key_j > key_i} -----------------
// Keys are distinct -> ranks are a permutation of 0..N-1 -> every slot < CAP written exactly once.
__global__ __launch_bounds__(256) void rank_select_kernel(
    const unsigned long long* __restrict__ keys, int* __restrict__ sel_idx,
    float* __restrict__ sel_p) {
  __shared__ unsigned long long kbuf[2048];  // 16 KiB
  const int e = blockIdx.y;
  const int i = blockIdx.x * 256 + threadIdx.x;
  const unsigned long long my = keys[(size_t)e * N_TOK + i];
  int rank = 0;
  for (int c = 0; c < N_TOK; c += 2048) {
    __syncthreads();
    for (int j = threadIdx.x; j < 2048; j += 256)
      kbuf[j] = keys[(size_t)e * N_TOK + c + j];
    __syncthreads();
#pragma unroll 8
    for (int j = 0; j < 2048; j += 2) {  // uniform addr -> LDS broadcast, conflict-free
      unsigned long long k0 = kbuf[j], k1 = kbuf[j + 1];
      rank += (k0 > my) + (k1 > my);
    }
  }
  if (rank < CAP) {
    sel_idx[e * CAP + rank] = i;
    sel_p[e * CAP + rank] = __uint_as_float((unsigned)(my >> 32));
  }
}

// ---------------- Gather selected token rows, f32 -> bf16 ----------------
__global__ __launch_bounds__(256) void gather_kernel(
    const float* __restrict__ x, const int* __restrict__ sel_idx,
    unsigned short* __restrict__ tok) {
  int row = blockIdx.x;
  int t = sel_idx[row];
  const float4* src = (const float4*)(x + (size_t)t * DMODEL);
  u16x4* dst = (u16x4*)(tok + (size_t)row * DMODEL);
  for (int i = threadIdx.x; i < DMODEL / 4; i += blockDim.x) {
    float4 v = src[i];
    u16x4 w = {f2bf(v.x), f2bf(v.y), f2bf(v.z), f2bf(v.w)};
    dst[i] = w;
  }
}

// ---------------- Transpose + convert: W[K][N] f32 -> WT[N][K] bf16, 64x64 tiles ----------------
__global__ __launch_bounds__(256) void transpose_convert_kernel(
    const float* __restrict__ W, unsigned short* __restrict__ WT, int K, int N) {
  __shared__ unsigned short tile[64][68];
  const size_t eoff = (size_t)blockIdx.z * (size_t)K * N;
  const float* Wp = W + eoff;
  unsigned short* Tp = WT + eoff;
  const int n0 = blockIdx.x * 64, k0 = blockIdx.y * 64;
  const int tid = threadIdx.x;
  const int nn4 = tid & 15, kk = tid >> 4;
#pragma unroll
  for (int p = 0; p < 4; ++p) {
    int k = kk + p * 16;
    float4 v = *(const float4*)&Wp[(size_t)(k0 + k) * N + n0 + nn4 * 4];
    tile[nn4 * 4 + 0][k] = f2bf(v.x);
    tile[nn4 * 4 + 1][k] = f2bf(v.y);
    tile[nn4 * 4 + 2][k] = f2bf(v.z);
    tile[nn4 * 4 + 3][k] = f2bf(v.w);
  }
  __syncthreads();
  const int nw = tid >> 4, cw = (tid & 15) * 4;
#pragma unroll
  for (int p = 0; p < 4; ++p) {
    int n = nw + p * 16;
    u16x4 v = *(const u16x4*)&tile[n][cw];
    *(u16x4*)&Tp[(size_t)(n0 + n) * K + k0 + cw] = v;
  }
}

// ---------------- 256x128 triple-buffered deep-pipelined bf16 GEMM ----------------
// C[M,N] = A[M,K] * Bt[N,K]^T (both bf16, k-contiguous rows). 512 thr = 8 waves (4Mx2N),
// per-wave 64x64 output = acc[4][4]. BK=64. LDS 144 KiB = 3 x (A 256x64 + B 128x64).
// Pipeline: iter t issues tile t+2 into buf (t+2)%3; end-of-iter wait:
//   while prefetching (pf): vmcnt(6)  -> tile t+1 landed, tile t+2's 6 stay in flight
//   once pf stops:          vmcnt(0)  -> drains the final tile's loads (r4 bug: vmcnt(6)
//                           here passes with 6 outstanding and reads stale LDS!)
// Buffer reuse is two barriers after its last read -> race-free.
// T2 swizzle both sides (verified 0 conflicts in r3): src chunk ^= row&7, read chunk ^= row&7.
// EPI 0: exact GELU -> bf16. EPI 1: atomicAdd(out[sel_idx[m]], acc*sel_p[m]).
template <int EPI>
__global__ __launch_bounds__(512) void gemm_kernel(
    const unsigned short* __restrict__ A, const unsigned short* __restrict__ Bt,
    void* __restrict__ C, const int* __restrict__ sel_idx, const float* __restrict__ sel_p,
    int M, int N, int K, size_t b_stride) {
  __shared__ unsigned short sh[73728];  // 3 bufs x 24576 ushorts (A 16384 + B 8192)
  const int tid = threadIdx.x;
  const int lane = tid & 63;
  const int w = tid >> 6;           // wave 0..7
  const int wm = w >> 1, wn = w & 1;

  // XCD-aware bijective swizzle (nwg is a multiple of 8 for all shapes used here)
  const int nwg = gridDim.x * gridDim.y;
  const int cpx = nwg >> 3;
  int linear = blockIdx.y * gridDim.x + blockIdx.x;
  linear = (linear & 7) * cpx + (linear >> 3);
  const int bx = linear & (gridDim.x - 1);
  const int by = linear >> __builtin_ctz(gridDim.x);
  const int m0 = by * 256, n0 = bx * 128;
  const unsigned short* Bp = Bt + (size_t)(m0 >> 11) * b_stride;

  f32x4 acc[4][4];
#pragma unroll
  for (int i = 0; i < 4; ++i)
#pragma unroll
    for (int j = 0; j < 4; ++j) acc[i][j] = (f32x4){0.f, 0.f, 0.f, 0.f};

  // staging: thread covers row (i*64 + tid>>3), source chunk (tid&7)^(row&7)  [involution]
  const int srow = tid >> 3;
  const int schunk = ((tid & 7) ^ (srow & 7)) * 8;
  const unsigned short* gA = A + (size_t)(m0 + srow) * K + schunk;
  const unsigned short* gB = Bp + (size_t)(n0 + srow) * K + schunk;

  // read addressing: swizzled k-chunk (ushort units); csw1 = csw0 ^ 32
  const int csw0 = (((lane >> 4) ^ (lane & 7)) << 3);
  const int arow = wm * 64 + (lane & 15);
  const int brow = wn * 64 + (lane & 15);

#define STAGE_A(buf, i, kt) \
  gload_lds16(gA + (size_t)((i) * 64) * K + (kt), &sh[(buf) * 24576 + ((i) * 64 + w * 8) * 64])
#define STAGE_B(buf, i, kt) \
  gload_lds16(gB + (size_t)((i) * 64) * K + (kt), &sh[(buf) * 24576 + 16384 + ((i) * 64 + w * 8) * 64])

  // prologue: tiles 0,1 -> bufs 0,1 (12 loads); tile 0 landed once <=6 outstanding
  STAGE_A(0, 0, 0); STAGE_A(0, 1, 0); STAGE_A(0, 2, 0); STAGE_A(0, 3, 0);
  STAGE_B(0, 0, 0); STAGE_B(0, 1, 0);
  STAGE_A(1, 0, 64); STAGE_A(1, 1, 64); STAGE_A(1, 2, 64); STAGE_A(1, 3, 64);
  STAGE_B(1, 0, 64); STAGE_B(1, 1, 64);
  asm volatile("s_waitcnt vmcnt(6)" ::: "memory");
  __builtin_amdgcn_s_barrier();

  const int NT = K >> 6;
  int buf = 0, pbuf = 2;
  for (int t = 0; t < NT; ++t) {
    const unsigned short* shA = &sh[buf * 24576];
    const unsigned short* shB = &sh[buf * 24576 + 16384];
    const bool pf = (t + 2) < NT;
    const int pkt = (t + 2) << 6;
    if (pf) { STAGE_A(pbuf, 0, pkt); STAGE_A(pbuf, 1, pkt); STAGE_A(pbuf, 2, pkt); }
    // ---- phase 0: kb=0 ----
    {
      s16x8 av[4], bv[4];
#pragma unroll
      for (int mf = 0; mf < 4; ++mf) av[mf] = *(const s16x8*)&shA[(arow + mf * 16) * 64 + csw0];
#pragma unroll
      for (int nf = 0; nf < 4; ++nf) bv[nf] = *(const s16x8*)&shB[(brow + nf * 16) * 64 + csw0];
      __builtin_amdgcn_s_setprio(1);
#pragma unroll
      for (int mf = 0; mf < 4; ++mf)
#pragma unroll
        for (int nf = 0; nf < 4; ++nf)
          acc[mf][nf] = __builtin_amdgcn_mfma_f32_16x16x32_bf16(av[mf], bv[nf], acc[mf][nf], 0, 0, 0);
      __builtin_amdgcn_s_setprio(0);
    }
    if (pf) { STAGE_A(pbuf, 3, pkt); STAGE_B(pbuf, 0, pkt); STAGE_B(pbuf, 1, pkt); }
    // ---- phase 1: kb=1 ----
    {
      const int csw1 = csw0 ^ 32;
      s16x8 av[4], bv[4];
#pragma unroll
      for (int mf = 0; mf < 4; ++mf) av[mf] = *(const s16x8*)&shA[(arow + mf * 16) * 64 + csw1];
#pragma unroll
      for (int nf = 0; nf < 4; ++nf) bv[nf] = *(const s16x8*)&shB[(brow + nf * 16) * 64 + csw1];
      __builtin_amdgcn_s_setprio(1);
#pragma unroll
      for (int mf = 0; mf < 4; ++mf)
#pragma unroll
        for (int nf = 0; nf < 4; ++nf)
          acc[mf][nf] = __builtin_amdgcn_mfma_f32_16x16x32_bf16(av[mf], bv[nf], acc[mf][nf], 0, 0, 0);
      __builtin_amdgcn_s_setprio(0);
    }
    // end-of-iter wait: need tile t+1 fully in LDS before next iter reads it.
    // outstanding here = (tile t+1 ? already counted down : 0) + tile t+2's 6 if pf.
    if (pf) {
      asm volatile("s_waitcnt vmcnt(6)" ::: "memory");  // t+1 landed, t+2 in flight
    } else {
      asm volatile("s_waitcnt vmcnt(0)" ::: "memory");  // final drain (r4 bugfix)
    }
    __builtin_amdgcn_s_barrier();
    buf = (buf == 2) ? 0 : buf + 1;
    pbuf = (pbuf == 2) ? 0 : pbuf + 1;
  }
#undef STAGE_A
#undef STAGE_B

  // epilogue (C frag layout: col = lane&15, row = (lane>>4)*4 + reg)
  if (EPI == 0) {
    unsigned short* Hc = (unsigned short*)C;
#pragma unroll
    for (int mf = 0; mf < 4; ++mf) {
      int rowb = m0 + wm * 64 + mf * 16 + ((lane >> 4) << 2);
#pragma unroll
      for (int nf = 0; nf < 4; ++nf) {
        int col = n0 + wn * 64 + nf * 16 + (lane & 15);
#pragma unroll
        for (int r = 0; r < 4; ++r) {
          float v = acc[mf][nf][r];
          float g = 0.5f * v * (1.0f + erff(v * 0.70710678118654752f));
          Hc[(size_t)(rowb + r) * N + col] = f2bf(g);
        }
      }
    }
  } else {
    float* O = (float*)C;
#pragma unroll
    for (int mf = 0; mf < 4; ++mf) {
      int rowb = m0 + wm * 64 + mf * 16 + ((lane >> 4) << 2);
      int tk[4];
      float pv[4];
#pragma unroll
      for (int r = 0; r < 4; ++r) { tk[r] = sel_idx[rowb + r]; pv[r] = sel_p[rowb + r]; }
#pragma unroll
      for (int nf = 0; nf < 4; ++nf) {
        int col = n0 + wn * 64 + nf * 16 + (lane & 15);
#pragma unroll
        for (int r = 0; r < 4; ++r)
          atomicAdd(&O[(size_t)tk[r] * DMODEL + col], acc[mf][nf][r] * pv[r]);
      }
    }
  }
}

extern "C" void kernel_launch(void* const* d_in, const int* in_sizes, int n_in,
                              void* d_out, int out_size, void* d_ws, size_t ws_size,
                              hipStream_t stream) {
  const float* x  = (const float*)d_in[0];
  const float* Wg = (const float*)d_in[1];
  const float* bg = (const float*)d_in[2];
  const float* W1 = (const float*)d_in[3];
  const float* W2 = (const float*)d_in[4];
  float* out = (float*)d_out;

  char* ws = (char*)d_ws;
  unsigned long long* keys = (unsigned long long*)ws;            // 4x8192x8 = 256 KiB
  int*   sel_idx = (int*)(ws + 262144);                          // 32 KiB
  float* sel_p   = (float*)(ws + 262144 + 32768);                // 32 KiB
  unsigned short* tok = (unsigned short*)(ws + 327680);          // 8192x2048 bf16 = 32 MiB
  const size_t tok_b = (size_t)N_TOK * DMODEL * 2;
  const size_t h_b   = (size_t)N_TOK * HDIM * 2;                 // 128 MiB
  const size_t w_b   = (size_t)NEXP * DMODEL * HDIM * 2;         // 128 MiB each
  const size_t base  = 327680 + tok_b;

  hipMemsetAsync(d_out, 0, (size_t)out_size * sizeof(float), stream);
  router_kernel<<<N_TOK / 4, 256, 0, stream>>>(x, Wg, bg, keys);
  rank_select_kernel<<<dim3(N_TOK / 256, NEXP), 256, 0, stream>>>(keys, sel_idx, sel_p);
  gather_kernel<<<NEXP * CAP, 256, 0, stream>>>(x, sel_idx, tok);

  if (ws_size >= base + h_b + 2 * w_b) {
    // Merged path: one dispatch per GEMM stage across all 4 experts.
    unsigned short* h   = (unsigned short*)(ws + base);
    unsigned short* W1T = (unsigned short*)(ws + base + h_b);
    unsigned short* W2T = (unsigned short*)(ws + base + h_b + w_b);
    transpose_convert_kernel<<<dim3(HDIM / 64, DMODEL / 64, NEXP), 256, 0, stream>>>(
        W1, W1T, DMODEL, HDIM);
    transpose_convert_kernel<<<dim3(DMODEL / 64, HDIM / 64, NEXP), 256, 0, stream>>>(
        W2, W2T, HDIM, DMODEL);
    gemm_kernel<0><<<dim3(HDIM / 128, N_TOK / 256), 512, 0, stream>>>(
        tok, W1T, h, nullptr, nullptr, N_TOK, HDIM, DMODEL, (size_t)DMODEL * HDIM);
    gemm_kernel<1><<<dim3(DMODEL / 128, N_TOK / 256), 512, 0, stream>>>(
        h, W2T, out, sel_idx, sel_p, N_TOK, DMODEL, HDIM, (size_t)DMODEL * HDIM);
  } else {
    // Fallback: per-expert, reuse one weight buffer + one h buffer.
    unsigned short* h    = (unsigned short*)(ws + base);                 // CAPxHDIM = 32 MiB
    unsigned short* wbuf = (unsigned short*)(ws + base + (size_t)CAP * HDIM * 2);
    for (int e = 0; e < NEXP; ++e) {
      transpose_convert_kernel<<<dim3(HDIM / 64, DMODEL / 64, 1), 256, 0, stream>>>(
          W1 + (size_t)e * DMODEL * HDIM, wbuf, DMODEL, HDIM);
      gemm_kernel<0><<<dim3(HDIM / 128, CAP / 256), 512, 0, stream>>>(
          tok + (size_t)e * CAP * DMODEL, wbuf, h, nullptr, nullptr, CAP, HDIM, DMODEL, 0);
      transpose_convert_kernel<<<dim3(DMODEL / 64, HDIM / 64, 1), 256, 0, stream>>>(
          W2 + (size_t)e * HDIM * DMODEL, wbuf, HDIM, DMODEL);
      gemm_kernel<1><<<dim3(DMODEL / 128, CAP / 256), 512, 0, stream>>>(
          h, wbuf, out, sel_idx + e * CAP, sel_p + e * CAP, CAP, DMODEL, HDIM, 0);
    }
  }
}

// Round 6
// 879.776 us; speedup vs baseline: 2.3189x; 1.0188x over previous
//
#include <hip/hip_runtime.h>
#include <hip/hip_bf16.h>
#include <math.h>
#include <stdint.h>

// Problem constants: B=4, T=2048, D=2048, E=4, H=8192, TOPK=2, CAP=N/E
#define N_TOK 8192
#define DMODEL 2048
#define NEXP 4
#define HDIM 8192
#define CAP 2048

typedef __attribute__((ext_vector_type(4))) float f32x4;
typedef __attribute__((ext_vector_type(8))) short s16x8;
typedef __attribute__((ext_vector_type(4))) unsigned short u16x4;

__device__ __forceinline__ unsigned short f2bf(float f) {
  __hip_bfloat16 h = __float2bfloat16(f);  // RNE
  return __builtin_bit_cast(unsigned short, h);
}

// global->LDS direct copy, 16 B per lane. LDS dest is wave-uniform base;
// HW writes lane i at base + i*16. Global source address is per-lane.
__device__ __forceinline__ void gload_lds16(const void* g, void* l) {
  __builtin_amdgcn_global_load_lds(
      (const __attribute__((address_space(1))) unsigned int*)(uintptr_t)g,
      (__attribute__((address_space(3))) unsigned int*)(unsigned int)(uintptr_t)l,
      16, 0, 0);
}

// ---------------- Router: logits = x @ Wg + bg (f64 accum), top-2 -> 64-bit sort keys --------
// key[e][i] = (float_bits(prob_e_i) << 32) | (0xFFFFFFFF - i); prob=0 for unassigned experts.
// Key order (desc) == lax.top_k order (prob desc, index asc). All keys distinct.
__global__ __launch_bounds__(256) void router_kernel(
    const float* __restrict__ x, const float* __restrict__ Wg,
    const float* __restrict__ bg, unsigned long long* __restrict__ keys) {
  int token = blockIdx.x * 4 + (threadIdx.x >> 6);
  int lane = threadIdx.x & 63;
  const float* xr = x + (size_t)token * DMODEL;
  double a0 = 0, a1 = 0, a2 = 0, a3 = 0;
  for (int i = lane; i < DMODEL; i += 64) {
    float xv = xr[i];
    float4 w = ((const float4*)Wg)[i];
    a0 += (double)xv * (double)w.x;
    a1 += (double)xv * (double)w.y;
    a2 += (double)xv * (double)w.z;
    a3 += (double)xv * (double)w.w;
  }
  for (int off = 32; off > 0; off >>= 1) {
    a0 += __shfl_down(a0, off);
    a1 += __shfl_down(a1, off);
    a2 += __shfl_down(a2, off);
    a3 += __shfl_down(a3, off);
  }
  if (lane == 0) {
    float l[4] = {(float)(a0 + (double)bg[0]), (float)(a1 + (double)bg[1]),
                  (float)(a2 + (double)bg[2]), (float)(a3 + (double)bg[3])};
    int e1 = 0;
    for (int e = 1; e < 4; ++e) if (l[e] > l[e1]) e1 = e;
    int e2 = (e1 == 0) ? 1 : 0;
    for (int e = e2 + 1; e < 4; ++e) { if (e == e1) continue; if (l[e] > l[e2]) e2 = e; }
    float d = l[e2] - l[e1];
    float ex = expf(d);
    float z = 1.0f + ex;
    float p1 = 1.0f / z, p2 = ex / z;
    unsigned lo = 0xFFFFFFFFu - (unsigned)token;
    for (int e = 0; e < 4; ++e) {
      unsigned hi = (e == e1) ? __float_as_uint(p1) : (e == e2) ? __float_as_uint(p2) : 0u;
      keys[(size_t)e * N_TOK + token] = ((unsigned long long)hi << 32) | lo;
    }
  }
}

// ---------------- Rank-based capacity selection: slot = #{j : key_j > key_i} -----------------
// Keys are distinct -> ranks are a permutation of 0..N-1 -> every slot < CAP written exactly once.
__global__ __launch_bounds__(256) void rank_select_kernel(
    const unsigned long long* __restrict__ keys, int* __restrict__ sel_idx,
    float* __restrict__ sel_p) {
  __shared__ unsigned long long kbuf[2048];  // 16 KiB
  const int e = blockIdx.y;
  const int i = blockIdx.x * 256 + threadIdx.x;
  const unsigned long long my = keys[(size_t)e * N_TOK + i];
  int rank = 0;
  for (int c = 0; c < N_TOK; c += 2048) {
    __syncthreads();
    for (int j = threadIdx.x; j < 2048; j += 256)
      kbuf[j] = keys[(size_t)e * N_TOK + c + j];
    __syncthreads();
#pragma unroll 8
    for (int j = 0; j < 2048; j += 2) {  // uniform addr -> LDS broadcast, conflict-free
      unsigned long long k0 = kbuf[j], k1 = kbuf[j + 1];
      rank += (k0 > my) + (k1 > my);
    }
  }
  if (rank < CAP) {
    sel_idx[e * CAP + rank] = i;
    sel_p[e * CAP + rank] = __uint_as_float((unsigned)(my >> 32));
  }
}

// ---------------- Gather selected token rows, f32 -> bf16 ----------------
__global__ __launch_bounds__(256) void gather_kernel(
    const float* __restrict__ x, const int* __restrict__ sel_idx,
    unsigned short* __restrict__ tok) {
  int row = blockIdx.x;
  int t = sel_idx[row];
  const float4* src = (const float4*)(x + (size_t)t * DMODEL);
  u16x4* dst = (u16x4*)(tok + (size_t)row * DMODEL);
  for (int i = threadIdx.x; i < DMODEL / 4; i += blockDim.x) {
    float4 v = src[i];
    u16x4 w = {f2bf(v.x), f2bf(v.y), f2bf(v.z), f2bf(v.w)};
    dst[i] = w;
  }
}

// ---------------- Transpose + convert: W[K][N] f32 -> WT[N][K] bf16, 64x64 tiles ----------------
__global__ __launch_bounds__(256) void transpose_convert_kernel(
    const float* __restrict__ W, unsigned short* __restrict__ WT, int K, int N) {
  __shared__ unsigned short tile[64][68];
  const size_t eoff = (size_t)blockIdx.z * (size_t)K * N;
  const float* Wp = W + eoff;
  unsigned short* Tp = WT + eoff;
  const int n0 = blockIdx.x * 64, k0 = blockIdx.y * 64;
  const int tid = threadIdx.x;
  const int nn4 = tid & 15, kk = tid >> 4;
#pragma unroll
  for (int p = 0; p < 4; ++p) {
    int k = kk + p * 16;
    float4 v = *(const float4*)&Wp[(size_t)(k0 + k) * N + n0 + nn4 * 4];
    tile[nn4 * 4 + 0][k] = f2bf(v.x);
    tile[nn4 * 4 + 1][k] = f2bf(v.y);
    tile[nn4 * 4 + 2][k] = f2bf(v.z);
    tile[nn4 * 4 + 3][k] = f2bf(v.w);
  }
  __syncthreads();
  const int nw = tid >> 4, cw = (tid & 15) * 4;
#pragma unroll
  for (int p = 0; p < 4; ++p) {
    int n = nw + p * 16;
    u16x4 v = *(const u16x4*)&tile[n][cw];
    *(u16x4*)&Tp[(size_t)(n0 + n) * K + k0 + cw] = v;
  }
}

// ---------------- 256x256 4-slot deep-pipelined bf16 GEMM, BK=32 ----------------
// C[M,N] = A[M,K] * Bt[N,K]^T (both bf16, k-contiguous). 512 thr = 8 waves (2Mx4N),
// per-wave 128x64 output = acc[8][4] (best FLOP/LDS-byte at this block size).
// LDS 128 KiB = 4 circular slots x (A 256x32 + B 256x32). Iter t computes slot t&3
// while issuing tile t+3 into slot (t-1)&3 (freed at the barrier ending tile t-1;
// all waves' reads completed before that barrier via compiler lgkmcnt -> race-free).
// Steady state: 8 loads (2 tiles) in flight across each barrier; vmcnt(8) retires
// exactly tile t+1. Epilogue peels vmcnt(4) -> vmcnt(0)  (r4 lesson: full final drain).
// Swizzle (both sides, rule 21): 64B rows, 4 chunks of 16B, chunk ^= (row>>1)&3
// -> 2-way residual aliasing only (free per m136); r3 measured 0 conflicts with
// the 128B-row variant of this scheme.
// EPI 0: exact GELU -> bf16. EPI 1: atomicAdd(out[sel_idx[m]], acc*sel_p[m]).
template <int EPI>
__global__ __launch_bounds__(512) void gemm_kernel(
    const unsigned short* __restrict__ A, const unsigned short* __restrict__ Bt,
    void* __restrict__ C, const int* __restrict__ sel_idx, const float* __restrict__ sel_p,
    int M, int N, int K, size_t b_stride) {
  __shared__ unsigned short sh[65536];  // 4 slots x 16384 ushorts (A 8192 + B 8192)
  const int tid = threadIdx.x;
  const int lane = tid & 63;
  const int w = tid >> 6;            // wave 0..7
  const int wm = w >> 2, wn = w & 3; // 2M x 4N

  // XCD-aware bijective swizzle (nwg multiple of 8, gridDim.x power of 2)
  const int nwg = gridDim.x * gridDim.y;
  const int cpx = nwg >> 3;
  int linear = blockIdx.y * gridDim.x + blockIdx.x;
  linear = (linear & 7) * cpx + (linear >> 3);
  const int bx = linear & (gridDim.x - 1);
  const int by = linear >> __builtin_ctz(gridDim.x);
  const int m0 = by * 256, n0 = bx * 256;
  const unsigned short* Bp = Bt + (size_t)(m0 >> 11) * b_stride;

  f32x4 acc[8][4];
#pragma unroll
  for (int i = 0; i < 8; ++i)
#pragma unroll
    for (int j = 0; j < 4; ++j) acc[i][j] = (f32x4){0.f, 0.f, 0.f, 0.f};

  // Staging: per tile, 4 gloads/thread (A rows 0-127 & 128-255, B same).
  // Wave w load-group covers 16 rows: row = grp*128 + w*16 + (lane>>2), 16B slot = lane&3.
  // Source chunk = slot ^ ((row>>1)&3)  [XOR involution of the LDS read swizzle].
  const int srow = (lane >> 2);
  const int schunk = ((lane & 3) ^ ((lane >> 3) & 3)) * 8;  // (row>>1)&3 == (lane>>3)&3 here
  const unsigned short* gA0 = A + (size_t)(m0 + w * 16 + srow) * K + schunk;
  const unsigned short* gA1 = gA0 + (size_t)128 * K;
  const unsigned short* gB0 = Bp + (size_t)(n0 + w * 16 + srow) * K + schunk;
  const unsigned short* gB1 = gB0 + (size_t)128 * K;
  const int ldsA0 = (w * 16) * 32;            // ushort index within slot
  const int ldsA1 = (128 + w * 16) * 32;
  const int ldsB0 = 8192 + (w * 16) * 32;
  const int ldsB1 = 8192 + (128 + w * 16) * 32;

  // Read addressing: row within tile, k-chunk kc = lane>>4 swizzled by (row>>1)&3.
  // (row>>1)&3 depends only on (lane&15) for frag rows -> per-lane constant.
  const int koff = (((lane >> 4) ^ ((lane >> 1) & 3)) << 3);  // elems
  const int arow = wm * 128 + (lane & 15);
  const int brow = wn * 64 + (lane & 15);

#define STAGE_AH(slot, kt) do { \
    gload_lds16(gA0 + (kt), &sh[(slot) * 16384 + ldsA0]); \
    gload_lds16(gA1 + (kt), &sh[(slot) * 16384 + ldsA1]); } while (0)
#define STAGE_BH(slot, kt) do { \
    gload_lds16(gB0 + (kt), &sh[(slot) * 16384 + ldsB0]); \
    gload_lds16(gB1 + (kt), &sh[(slot) * 16384 + ldsB1]); } while (0)

#define COMPUTE_TILE(slot) do { \
    const unsigned short* shA = &sh[(slot) * 16384]; \
    const unsigned short* shB = shA + 8192; \
    s16x8 av[4], bv[4]; \
    _Pragma("unroll") \
    for (int nf = 0; nf < 4; ++nf) bv[nf] = *(const s16x8*)&shB[(brow + nf * 16) * 32 + koff]; \
    _Pragma("unroll") \
    for (int mf = 0; mf < 4; ++mf) av[mf] = *(const s16x8*)&shA[(arow + mf * 16) * 32 + koff]; \
    __builtin_amdgcn_s_setprio(1); \
    _Pragma("unroll") \
    for (int mf = 0; mf < 4; ++mf) \
      _Pragma("unroll") \
      for (int nf = 0; nf < 4; ++nf) \
        acc[mf][nf] = __builtin_amdgcn_mfma_f32_16x16x32_bf16(av[mf], bv[nf], acc[mf][nf], 0, 0, 0); \
    __builtin_amdgcn_s_setprio(0); \
    PF_B \
    _Pragma("unroll") \
    for (int mf = 0; mf < 4; ++mf) av[mf] = *(const s16x8*)&shA[(arow + 64 + mf * 16) * 32 + koff]; \
    __builtin_amdgcn_s_setprio(1); \
    _Pragma("unroll") \
    for (int mf = 0; mf < 4; ++mf) \
      _Pragma("unroll") \
      for (int nf = 0; nf < 4; ++nf) \
        acc[4 + mf][nf] = __builtin_amdgcn_mfma_f32_16x16x32_bf16(av[mf], bv[nf], acc[4 + mf][nf], 0, 0, 0); \
    __builtin_amdgcn_s_setprio(0); \
  } while (0)

  // prologue: tiles 0,1,2 into slots 0,1,2 (12 loads); tile 0 landed at vmcnt(8)
  STAGE_AH(0, 0); STAGE_BH(0, 0);
  STAGE_AH(1, 32); STAGE_BH(1, 32);
  STAGE_AH(2, 64); STAGE_BH(2, 64);
  asm volatile("s_waitcnt vmcnt(8)" ::: "memory");
  __builtin_amdgcn_s_barrier();

  const int NT = K >> 5;
  int t = 0;
  for (; t + 3 < NT; ++t) {
    const int slot = t & 3, psl = (t + 3) & 3;
    const int pkt = (t + 3) << 5;
    STAGE_AH(psl, pkt);
#define PF_B STAGE_BH(psl, pkt);
    COMPUTE_TILE(slot);
#undef PF_B
    asm volatile("s_waitcnt vmcnt(8)" ::: "memory");  // tile t+1 landed; t+2,t+3 in flight
    __builtin_amdgcn_s_barrier();
  }
#define PF_B
  // t = NT-3: no new issue; retire tile t+1, keep t+2's 4 loads in flight
  COMPUTE_TILE(t & 3);
  asm volatile("s_waitcnt vmcnt(4)" ::: "memory");
  __builtin_amdgcn_s_barrier();
  ++t;
  // t = NT-2: final drain (r4 lesson)
  COMPUTE_TILE(t & 3);
  asm volatile("s_waitcnt vmcnt(0)" ::: "memory");
  __builtin_amdgcn_s_barrier();
  ++t;
  // t = NT-1: last tile, no wait needed after
  COMPUTE_TILE(t & 3);
#undef PF_B
#undef COMPUTE_TILE
#undef STAGE_AH
#undef STAGE_BH

  // epilogue (C frag layout: col = lane&15, row = (lane>>4)*4 + reg)
  if (EPI == 0) {
    unsigned short* Hc = (unsigned short*)C;
#pragma unroll
    for (int mf = 0; mf < 8; ++mf) {
      int rowb = m0 + wm * 128 + mf * 16 + ((lane >> 4) << 2);
#pragma unroll
      for (int nf = 0; nf < 4; ++nf) {
        int col = n0 + wn * 64 + nf * 16 + (lane & 15);
#pragma unroll
        for (int r = 0; r < 4; ++r) {
          float v = acc[mf][nf][r];
          float g = 0.5f * v * (1.0f + erff(v * 0.70710678118654752f));
          Hc[(size_t)(rowb + r) * N + col] = f2bf(g);
        }
      }
    }
  } else {
    float* O = (float*)C;
#pragma unroll
    for (int mf = 0; mf < 8; ++mf) {
      int rowb = m0 + wm * 128 + mf * 16 + ((lane >> 4) << 2);
      int tk[4];
      float pv[4];
#pragma unroll
      for (int r = 0; r < 4; ++r) { tk[r] = sel_idx[rowb + r]; pv[r] = sel_p[rowb + r]; }
#pragma unroll
      for (int nf = 0; nf < 4; ++nf) {
        int col = n0 + wn * 64 + nf * 16 + (lane & 15);
#pragma unroll
        for (int r = 0; r < 4; ++r)
          atomicAdd(&O[(size_t)tk[r] * DMODEL + col], acc[mf][nf][r] * pv[r]);
      }
    }
  }
}

extern "C" void kernel_launch(void* const* d_in, const int* in_sizes, int n_in,
                              void* d_out, int out_size, void* d_ws, size_t ws_size,
                              hipStream_t stream) {
  const float* x  = (const float*)d_in[0];
  const float* Wg = (const float*)d_in[1];
  const float* bg = (const float*)d_in[2];
  const float* W1 = (const float*)d_in[3];
  const float* W2 = (const float*)d_in[4];
  float* out = (float*)d_out;

  char* ws = (char*)d_ws;
  unsigned long long* keys = (unsigned long long*)ws;            // 4x8192x8 = 256 KiB
  int*   sel_idx = (int*)(ws + 262144);                          // 32 KiB
  float* sel_p   = (float*)(ws + 262144 + 32768);                // 32 KiB
  unsigned short* tok = (unsigned short*)(ws + 327680);          // 8192x2048 bf16 = 32 MiB
  const size_t tok_b = (size_t)N_TOK * DMODEL * 2;
  const size_t h_b   = (size_t)N_TOK * HDIM * 2;                 // 128 MiB
  const size_t w_b   = (size_t)NEXP * DMODEL * HDIM * 2;         // 128 MiB each
  const size_t base  = 327680 + tok_b;

  hipMemsetAsync(d_out, 0, (size_t)out_size * sizeof(float), stream);
  router_kernel<<<N_TOK / 4, 256, 0, stream>>>(x, Wg, bg, keys);
  rank_select_kernel<<<dim3(N_TOK / 256, NEXP), 256, 0, stream>>>(keys, sel_idx, sel_p);
  gather_kernel<<<NEXP * CAP, 256, 0, stream>>>(x, sel_idx, tok);

  if (ws_size >= base + h_b + 2 * w_b) {
    // Merged path: one dispatch per GEMM stage across all 4 experts.
    unsigned short* h   = (unsigned short*)(ws + base);
    unsigned short* W1T = (unsigned short*)(ws + base + h_b);
    unsigned short* W2T = (unsigned short*)(ws + base + h_b + w_b);
    transpose_convert_kernel<<<dim3(HDIM / 64, DMODEL / 64, NEXP), 256, 0, stream>>>(
        W1, W1T, DMODEL, HDIM);
    transpose_convert_kernel<<<dim3(DMODEL / 64, HDIM / 64, NEXP), 256, 0, stream>>>(
        W2, W2T, HDIM, DMODEL);
    gemm_kernel<0><<<dim3(HDIM / 256, N_TOK / 256), 512, 0, stream>>>(
        tok, W1T, h, nullptr, nullptr, N_TOK, HDIM, DMODEL, (size_t)DMODEL * HDIM);
    gemm_kernel<1><<<dim3(DMODEL / 256, N_TOK / 256), 512, 0, stream>>>(
        h, W2T, out, sel_idx, sel_p, N_TOK, DMODEL, HDIM, (size_t)DMODEL * HDIM);
  } else {
    // Fallback: per-expert, reuse one weight buffer + one h buffer.
    unsigned short* h    = (unsigned short*)(ws + base);                 // CAPxHDIM = 32 MiB
    unsigned short* wbuf = (unsigned short*)(ws + base + (size_t)CAP * HDIM * 2);
    for (int e = 0; e < NEXP; ++e) {
      transpose_convert_kernel<<<dim3(HDIM / 64, DMODEL / 64, 1), 256, 0, stream>>>(
          W1 + (size_t)e * DMODEL * HDIM, wbuf, DMODEL, HDIM);
      gemm_kernel<0><<<dim3(HDIM / 256, CAP / 256), 512, 0, stream>>>(
          tok + (size_t)e * CAP * DMODEL, wbuf, h, nullptr, nullptr, CAP, HDIM, DMODEL, 0);
      transpose_convert_kernel<<<dim3(DMODEL / 64, HDIM / 64, 1), 256, 0, stream>>>(
          W2 + (size_t)e * HDIM * DMODEL, wbuf, HDIM, DMODEL);
      gemm_kernel<1><<<dim3(DMODEL / 256, CAP / 256), 512, 0, stream>>>(
          h, wbuf, out, sel_idx + e * CAP, sel_p + e * CAP, CAP, DMODEL, HDIM, 0);
    }
  }
}